// Round 1
// baseline (1470.194 us; speedup 1.0000x reference)
//
#include <hip/hip_runtime.h>

#define N_NODES 100000
#define N_EDGES 3200000

// ---------------------------------------------------------------------------
// Kernel A: feat = node_feat @ Wfc.T  (N x 64), el/er = sum(feat*attn, -1)
// Wfc stored transposed in LDS (T[k][j]) so lane j reads T[k*64+j] conflict-free.
// Each wave processes 4 nodes per iteration to amortize LDS reads 4x.
// ---------------------------------------------------------------------------
__global__ __launch_bounds__(256) void node_proj(
    const float* __restrict__ node_feat,
    const float* __restrict__ Wfc,
    const float* __restrict__ attn_l,
    const float* __restrict__ attn_r,
    float* __restrict__ feat,
    float* __restrict__ el,
    float* __restrict__ er)
{
    __shared__ float T[128 * 64];   // 32 KiB: T[k*64 + j] = Wfc[j*128 + k]
    const int tid = threadIdx.x;
    for (int i = tid; i < 64 * 128; i += 256) {
        int j = i >> 7, k = i & 127;
        T[k * 64 + j] = Wfc[i];
    }
    __syncthreads();

    const int lane = tid & 63;
    const float al = attn_l[lane];
    const float ar = attn_r[lane];
    const int gw = blockIdx.x * 4 + (tid >> 6);
    const int nw = gridDim.x * 4;

    for (int g = gw; g * 4 < N_NODES; g += nw) {
        const int n0 = g * 4;
        const float4* __restrict__ x0 = (const float4*)(node_feat + (size_t)(n0 + 0) * 128);
        const float4* __restrict__ x1 = (const float4*)(node_feat + (size_t)(n0 + 1) * 128);
        const float4* __restrict__ x2 = (const float4*)(node_feat + (size_t)(n0 + 2) * 128);
        const float4* __restrict__ x3 = (const float4*)(node_feat + (size_t)(n0 + 3) * 128);

        float acc0 = 0.f, acc1 = 0.f, acc2 = 0.f, acc3 = 0.f;
        #pragma unroll 8
        for (int k4 = 0; k4 < 32; ++k4) {
            const float4 v0 = x0[k4], v1 = x1[k4], v2 = x2[k4], v3 = x3[k4];
            const int kb = k4 * 4;
            const float w0 = T[(kb + 0) * 64 + lane];
            const float w1 = T[(kb + 1) * 64 + lane];
            const float w2 = T[(kb + 2) * 64 + lane];
            const float w3 = T[(kb + 3) * 64 + lane];
            acc0 = fmaf(v0.x, w0, acc0); acc0 = fmaf(v0.y, w1, acc0);
            acc0 = fmaf(v0.z, w2, acc0); acc0 = fmaf(v0.w, w3, acc0);
            acc1 = fmaf(v1.x, w0, acc1); acc1 = fmaf(v1.y, w1, acc1);
            acc1 = fmaf(v1.z, w2, acc1); acc1 = fmaf(v1.w, w3, acc1);
            acc2 = fmaf(v2.x, w0, acc2); acc2 = fmaf(v2.y, w1, acc2);
            acc2 = fmaf(v2.z, w2, acc2); acc2 = fmaf(v2.w, w3, acc2);
            acc3 = fmaf(v3.x, w0, acc3); acc3 = fmaf(v3.y, w1, acc3);
            acc3 = fmaf(v3.z, w2, acc3); acc3 = fmaf(v3.w, w3, acc3);
        }

        feat[(size_t)(n0 + 0) * 64 + lane] = acc0;
        feat[(size_t)(n0 + 1) * 64 + lane] = acc1;
        feat[(size_t)(n0 + 2) * 64 + lane] = acc2;
        feat[(size_t)(n0 + 3) * 64 + lane] = acc3;

        const float accs[4] = {acc0, acc1, acc2, acc3};
        #pragma unroll
        for (int i = 0; i < 4; ++i) {
            float vl = accs[i] * al;
            float vr = accs[i] * ar;
            #pragma unroll
            for (int off = 8; off >= 1; off >>= 1) {
                vl += __shfl_xor(vl, off);
                vr += __shfl_xor(vr, off);
            }
            if ((lane & 15) == 0) {
                el[(size_t)(n0 + i) * 4 + (lane >> 4)] = vl;
                er[(size_t)(n0 + i) * 4 + (lane >> 4)] = vr;
            }
        }
    }
}

// ---------------------------------------------------------------------------
// Kernel B: per edge, ee_c = exp(lrelu(el[src][c]+er[dst][c]) * (We[c]·ef)),
// atomically accumulate softmax denominators s[dst][c].
// ---------------------------------------------------------------------------
__global__ __launch_bounds__(256) void edge_sum(
    const float* __restrict__ edge_feat,
    const int* __restrict__ src,
    const int* __restrict__ dst,
    const float* __restrict__ We,
    const float* __restrict__ el,
    const float* __restrict__ er,
    float* __restrict__ s)
{
    const int e = blockIdx.x * 256 + threadIdx.x;
    if (e >= N_EDGES) return;

    const int si = src[e];
    const int di = dst[e];
    const float4 ef = ((const float4*)edge_feat)[e];
    const float4 l4 = ((const float4*)el)[si];
    const float4 r4 = ((const float4*)er)[di];
    const float4 w0 = ((const float4*)We)[0];
    const float4 w1 = ((const float4*)We)[1];
    const float4 w2 = ((const float4*)We)[2];
    const float4 w3 = ((const float4*)We)[3];

    const float l[4] = {l4.x, l4.y, l4.z, l4.w};
    const float r[4] = {r4.x, r4.y, r4.z, r4.w};
    const float efc[4] = {
        w0.x * ef.x + w0.y * ef.y + w0.z * ef.z + w0.w * ef.w,
        w1.x * ef.x + w1.y * ef.y + w1.z * ef.z + w1.w * ef.w,
        w2.x * ef.x + w2.y * ef.y + w2.z * ef.z + w2.w * ef.w,
        w3.x * ef.x + w3.y * ef.y + w3.z * ef.z + w3.w * ef.w};

    #pragma unroll
    for (int c = 0; c < 4; ++c) {
        float t = l[c] + r[c];
        t = t > 0.f ? t : 0.2f * t;
        const float ee = __expf(t * efc[c]);
        atomicAdd(&s[(size_t)di * 4 + c], ee);
    }
}

// ---------------------------------------------------------------------------
// Kernel C: one wave per edge. Lane j -> (c = j>>4, f = j&15).
// Recompute ee (cheaper than storing 51 MB), a = ee/s[dst][c],
// rst[dst][j] += a * feat[src][j] via coalesced 64-lane atomicAdd.
// ---------------------------------------------------------------------------
__global__ __launch_bounds__(256) void edge_aggregate(
    const float* __restrict__ edge_feat,
    const int* __restrict__ src,
    const int* __restrict__ dst,
    const float* __restrict__ We,
    const float* __restrict__ el,
    const float* __restrict__ er,
    const float* __restrict__ s,
    const float* __restrict__ feat,
    float* __restrict__ rst)
{
    const int e = (int)((blockIdx.x * 256 + threadIdx.x) >> 6);
    const int lane = threadIdx.x & 63;
    if (e >= N_EDGES) return;

    const int si = src[e];
    const int di = dst[e];
    const int c = lane >> 4;

    const float lc = el[(size_t)si * 4 + c];
    const float rc = er[(size_t)di * 4 + c];
    float t = lc + rc;
    t = t > 0.f ? t : 0.2f * t;

    const float4 ef = ((const float4*)edge_feat)[e];
    const float* wrow = We + c * 4;
    const float efc = wrow[0] * ef.x + wrow[1] * ef.y + wrow[2] * ef.z + wrow[3] * ef.w;

    const float ee = __expf(t * efc);
    const float a = ee / s[(size_t)di * 4 + c];

    const float fv = feat[(size_t)si * 64 + lane];
    atomicAdd(&rst[(size_t)di * 64 + lane], a * fv);
}

// ---------------------------------------------------------------------------
extern "C" void kernel_launch(void* const* d_in, const int* in_sizes, int n_in,
                              void* d_out, int out_size, void* d_ws, size_t ws_size,
                              hipStream_t stream)
{
    const float* node_feat = (const float*)d_in[0];
    const float* edge_feat = (const float*)d_in[1];
    const int*   src       = (const int*)d_in[2];
    const int*   dst       = (const int*)d_in[3];
    const float* Wfc       = (const float*)d_in[4];
    const float* We        = (const float*)d_in[5];
    const float* attn_l    = (const float*)d_in[6];
    const float* attn_r    = (const float*)d_in[7];
    float* rst = (float*)d_out;

    char* ws = (char*)d_ws;
    float* feat = (float*)(ws);                         // N*64 f32 = 25.6 MB
    float* el   = (float*)(ws + 25600000);              // N*4  f32 =  1.6 MB
    float* er   = (float*)(ws + 27200000);              // N*4  f32 =  1.6 MB
    float* s    = (float*)(ws + 28800000);              // N*4  f32 =  1.6 MB

    hipMemsetAsync(s, 0, (size_t)N_NODES * 4 * sizeof(float), stream);
    hipMemsetAsync(rst, 0, (size_t)N_NODES * 64 * sizeof(float), stream);

    node_proj<<<1250, 256, 0, stream>>>(node_feat, Wfc, attn_l, attn_r, feat, el, er);
    edge_sum<<<(N_EDGES + 255) / 256, 256, 0, stream>>>(edge_feat, src, dst, We, el, er, s);
    edge_aggregate<<<N_EDGES / 4, 256, 0, stream>>>(edge_feat, src, dst, We, el, er, s, feat, rst);
}

// Round 2
// 742.790 us; speedup vs baseline: 1.9793x; 1.9793x over previous
//
#include <hip/hip_runtime.h>

#define N_NODES 100000
#define N_EDGES 3200000
#define SCAN_CHUNK 4096   // 256 threads x 16 elems
#define SCAN_BLOCKS 25    // ceil(100000 / 4096)

// ---------------------------------------------------------------------------
// Kernel A: feat = node_feat @ Wfc.T  (N x 64), el/er = sum(feat*attn, -1)
// ---------------------------------------------------------------------------
__global__ __launch_bounds__(256) void node_proj(
    const float* __restrict__ node_feat,
    const float* __restrict__ Wfc,
    const float* __restrict__ attn_l,
    const float* __restrict__ attn_r,
    float* __restrict__ feat,
    float* __restrict__ el,
    float* __restrict__ er)
{
    __shared__ float T[128 * 64];   // 32 KiB: T[k*64 + j] = Wfc[j*128 + k]
    const int tid = threadIdx.x;
    for (int i = tid; i < 64 * 128; i += 256) {
        int j = i >> 7, k = i & 127;
        T[k * 64 + j] = Wfc[i];
    }
    __syncthreads();

    const int lane = tid & 63;
    const float al = attn_l[lane];
    const float ar = attn_r[lane];
    const int gw = blockIdx.x * 4 + (tid >> 6);
    const int nw = gridDim.x * 4;

    for (int g = gw; g * 4 < N_NODES; g += nw) {
        const int n0 = g * 4;
        const float4* __restrict__ x0 = (const float4*)(node_feat + (size_t)(n0 + 0) * 128);
        const float4* __restrict__ x1 = (const float4*)(node_feat + (size_t)(n0 + 1) * 128);
        const float4* __restrict__ x2 = (const float4*)(node_feat + (size_t)(n0 + 2) * 128);
        const float4* __restrict__ x3 = (const float4*)(node_feat + (size_t)(n0 + 3) * 128);

        float acc0 = 0.f, acc1 = 0.f, acc2 = 0.f, acc3 = 0.f;
        #pragma unroll 8
        for (int k4 = 0; k4 < 32; ++k4) {
            const float4 v0 = x0[k4], v1 = x1[k4], v2 = x2[k4], v3 = x3[k4];
            const int kb = k4 * 4;
            const float w0 = T[(kb + 0) * 64 + lane];
            const float w1 = T[(kb + 1) * 64 + lane];
            const float w2 = T[(kb + 2) * 64 + lane];
            const float w3 = T[(kb + 3) * 64 + lane];
            acc0 = fmaf(v0.x, w0, acc0); acc0 = fmaf(v0.y, w1, acc0);
            acc0 = fmaf(v0.z, w2, acc0); acc0 = fmaf(v0.w, w3, acc0);
            acc1 = fmaf(v1.x, w0, acc1); acc1 = fmaf(v1.y, w1, acc1);
            acc1 = fmaf(v1.z, w2, acc1); acc1 = fmaf(v1.w, w3, acc1);
            acc2 = fmaf(v2.x, w0, acc2); acc2 = fmaf(v2.y, w1, acc2);
            acc2 = fmaf(v2.z, w2, acc2); acc2 = fmaf(v2.w, w3, acc2);
            acc3 = fmaf(v3.x, w0, acc3); acc3 = fmaf(v3.y, w1, acc3);
            acc3 = fmaf(v3.z, w2, acc3); acc3 = fmaf(v3.w, w3, acc3);
        }

        feat[(size_t)(n0 + 0) * 64 + lane] = acc0;
        feat[(size_t)(n0 + 1) * 64 + lane] = acc1;
        feat[(size_t)(n0 + 2) * 64 + lane] = acc2;
        feat[(size_t)(n0 + 3) * 64 + lane] = acc3;

        const float accs[4] = {acc0, acc1, acc2, acc3};
        #pragma unroll
        for (int i = 0; i < 4; ++i) {
            float vl = accs[i] * al;
            float vr = accs[i] * ar;
            #pragma unroll
            for (int off = 8; off >= 1; off >>= 1) {
                vl += __shfl_xor(vl, off);
                vr += __shfl_xor(vr, off);
            }
            if ((lane & 15) == 0) {
                el[(size_t)(n0 + i) * 4 + (lane >> 4)] = vl;
                er[(size_t)(n0 + i) * 4 + (lane >> 4)] = vr;
            }
        }
    }
}

// ---------------------------------------------------------------------------
// CSR build: histogram -> scan -> scatter
// ---------------------------------------------------------------------------
__global__ __launch_bounds__(256) void hist(const int* __restrict__ dst,
                                            int* __restrict__ counts)
{
    const int e = blockIdx.x * 256 + threadIdx.x;
    if (e < N_EDGES) atomicAdd(&counts[dst[e]], 1);
}

__global__ __launch_bounds__(256) void scan1(const int* __restrict__ counts,
                                             int* __restrict__ offsets,
                                             int* __restrict__ blockSums)
{
    __shared__ int lds[256];
    const int b = blockIdx.x, t = threadIdx.x;
    const int base = b * SCAN_CHUNK + t * 16;
    int v[16];
    int sum = 0;
    #pragma unroll
    for (int i = 0; i < 16; ++i) {
        int idx = base + i;
        v[i] = (idx < N_NODES) ? counts[idx] : 0;
        sum += v[i];
    }
    lds[t] = sum;
    __syncthreads();
    int x = sum;
    for (int off = 1; off < 256; off <<= 1) {
        int y = (t >= off) ? lds[t - off] : 0;
        __syncthreads();
        x += y;
        lds[t] = x;
        __syncthreads();
    }
    if (t == 255) blockSums[b] = x;
    int run = x - sum;   // exclusive
    #pragma unroll
    for (int i = 0; i < 16; ++i) {
        int idx = base + i;
        if (idx < N_NODES) offsets[idx] = run;
        run += v[i];
    }
}

__global__ void scan2(int* __restrict__ blockSums, int nb)
{
    if (threadIdx.x == 0 && blockIdx.x == 0) {
        int acc = 0;
        for (int i = 0; i < nb; ++i) { int v = blockSums[i]; blockSums[i] = acc; acc += v; }
    }
}

__global__ __launch_bounds__(256) void scan3(int* __restrict__ offsets,
                                             int* __restrict__ cursor,
                                             const int* __restrict__ blockSums)
{
    const int idx = blockIdx.x * 256 + threadIdx.x;
    if (idx < N_NODES) {
        int o = offsets[idx] + blockSums[idx >> 12];   // 4096 = 1<<12
        offsets[idx] = o;
        cursor[idx] = o;
    }
}

__global__ __launch_bounds__(256) void scatter(const int* __restrict__ src,
                                               const int* __restrict__ dst,
                                               int* __restrict__ cursor,
                                               int* __restrict__ ssrc,
                                               int* __restrict__ seid)
{
    const int e = blockIdx.x * 256 + threadIdx.x;
    if (e >= N_EDGES) return;
    const int d = dst[e];
    const int pos = atomicAdd(&cursor[d], 1);
    ssrc[pos] = src[e];
    seid[pos] = e;
}

// ---------------------------------------------------------------------------
// Aggregation: one wave per dst node. Lane j -> (c = j>>4, f = j&15).
// rst[dst] = (sum_e ee * feat[src]) / (sum_e ee).  No atomics, single store.
// ---------------------------------------------------------------------------
__global__ __launch_bounds__(256) void aggregate(
    const float* __restrict__ edge_feat,
    const float* __restrict__ We,
    const float* __restrict__ el,
    const float* __restrict__ er,
    const int* __restrict__ offsets,
    const int* __restrict__ counts,
    const int* __restrict__ ssrc,
    const int* __restrict__ seid,
    const float* __restrict__ feat,
    float* __restrict__ rst)
{
    const int node = (int)((blockIdx.x * 256 + threadIdx.x) >> 6);
    const int lane = threadIdx.x & 63;
    if (node >= N_NODES) return;
    const int c = lane >> 4;

    const float w0 = We[c * 4 + 0], w1 = We[c * 4 + 1];
    const float w2 = We[c * 4 + 2], w3 = We[c * 4 + 3];
    const float rc = er[(size_t)node * 4 + c];
    const int start = offsets[node];
    const int deg = counts[node];

    float acc = 0.f, ssum = 0.f;
    for (int base = 0; base < deg; base += 64) {
        const int n = min(64, deg - base);
        int si_l = 0, eid_l = 0;
        if (lane < n) {
            si_l  = ssrc[start + base + lane];
            eid_l = seid[start + base + lane];
        }
        for (int i = 0; i < n; ++i) {
            const int si  = __shfl(si_l, i);
            const int eid = __shfl(eid_l, i);
            const float4 ef = ((const float4*)edge_feat)[eid];
            const float lc = el[(size_t)si * 4 + c];
            float t = lc + rc;
            t = t > 0.f ? t : 0.2f * t;
            const float ee = __expf(t * (w0 * ef.x + w1 * ef.y + w2 * ef.z + w3 * ef.w));
            const float fv = feat[(size_t)si * 64 + lane];
            acc = fmaf(ee, fv, acc);
            ssum += ee;
        }
    }
    rst[(size_t)node * 64 + lane] = (deg > 0) ? acc / ssum : 0.f;
}

// ---------------------------------------------------------------------------
extern "C" void kernel_launch(void* const* d_in, const int* in_sizes, int n_in,
                              void* d_out, int out_size, void* d_ws, size_t ws_size,
                              hipStream_t stream)
{
    const float* node_feat = (const float*)d_in[0];
    const float* edge_feat = (const float*)d_in[1];
    const int*   src       = (const int*)d_in[2];
    const int*   dst       = (const int*)d_in[3];
    const float* Wfc       = (const float*)d_in[4];
    const float* We        = (const float*)d_in[5];
    const float* attn_l    = (const float*)d_in[6];
    const float* attn_r    = (const float*)d_in[7];
    float* rst = (float*)d_out;

    char* ws = (char*)d_ws;
    float* feat      = (float*)(ws);                  // 25,600,000 B
    float* el        = (float*)(ws + 25600000);       //  1,600,000 B
    float* er        = (float*)(ws + 27200000);       //  1,600,000 B
    int*   counts    = (int*)  (ws + 28800000);       //    400,000 B
    int*   offsets   = (int*)  (ws + 29200000);       //    400,000 B
    int*   cursor    = (int*)  (ws + 29600000);       //    400,000 B
    int*   blockSums = (int*)  (ws + 30000000);       //        256 B
    int*   ssrc      = (int*)  (ws + 30400000);       // 12,800,000 B
    int*   seid      = (int*)  (ws + 43200000);       // 12,800,000 B
                                                      // total 56 MB

    hipMemsetAsync(counts, 0, (size_t)N_NODES * sizeof(int), stream);

    node_proj<<<1250, 256, 0, stream>>>(node_feat, Wfc, attn_l, attn_r, feat, el, er);
    hist<<<(N_EDGES + 255) / 256, 256, 0, stream>>>(dst, counts);
    scan1<<<SCAN_BLOCKS, 256, 0, stream>>>(counts, offsets, blockSums);
    scan2<<<1, 64, 0, stream>>>(blockSums, SCAN_BLOCKS);
    scan3<<<(N_NODES + 255) / 256, 256, 0, stream>>>(offsets, cursor, blockSums);
    scatter<<<(N_EDGES + 255) / 256, 256, 0, stream>>>(src, dst, cursor, ssrc, seid);
    aggregate<<<(N_NODES * 64 + 255) / 256, 256, 0, stream>>>(
        edge_feat, We, el, er, offsets, counts, ssrc, seid, feat, rst);
}